// Round 1
// 505.728 us; speedup vs baseline: 1.0355x; 1.0355x over previous
//
#include <hip/hip_runtime.h>

// Problem constants (from reference file)
#define N0_SRC 200000
#define N1_DST 50000
#define N2_DST 12000
#define N3_DST 3000
#define NTOT_DST 65000   // N1+N2+N3 (multiple of 4; scan uses 64 blocks)
#define DH 256           // D_IN == D_H == 256
#define DOUT 64
#define EMAX_TOT 650000  // E0+E1+E2

typedef __attribute__((ext_vector_type(8))) short short8;
typedef __attribute__((ext_vector_type(4))) float f32x4;

__device__ __forceinline__ ushort f2bf(float f) {
    union { float f; uint32_t u; } v; v.f = f;
    uint32_t r = (v.u + 0x7FFF + ((v.u >> 16) & 1)) >> 16;  // RNE
    return (ushort)r;
}
__device__ __forceinline__ float bf2f(ushort u) {
    union { uint32_t u; float f; } v; v.u = ((uint32_t)u) << 16;
    return v.f;
}

// global -> LDS direct copy, 16B per lane. LDS dest is wave-uniform base +
// lane*16 (m104); caller passes the wave-uniform LDS base pointer.
__device__ __forceinline__ void gload16(const ushort* g, ushort* l) {
    __builtin_amdgcn_global_load_lds(
        (const __attribute__((address_space(1))) unsigned int*)g,
        (__attribute__((address_space(3))) unsigned int*)l,
        16, 0, 0);
}

// ---------------------------------------------------------------------------
// fp32 -> bf16 bulk convert (n multiple of 4)
// ---------------------------------------------------------------------------
__global__ void f32_to_bf16_kernel(const float* __restrict__ in,
                                   ushort* __restrict__ out, long n) {
    long i = ((long)blockIdx.x * 256 + threadIdx.x) * 4;
    if (i >= n) return;
    float4 v = *(const float4*)(in + i);
    ushort4 o;
    o.x = f2bf(v.x); o.y = f2bf(v.y); o.z = f2bf(v.z); o.w = f2bf(v.w);
    *(ushort4*)(out + i) = o;
}

// ---------------------------------------------------------------------------
// All six weight transposes in one launch: W[K][N] fp32 -> Wt[N][K] bf16.
// grid = (256, 6). blockIdx.y==0 blocks also zero the CSR count array
// (65536 threads cover NTOT_DST) -- saves the hipMemsetAsync dispatch.
// ---------------------------------------------------------------------------
__global__ void transpose_w_all(const float* __restrict__ W0, const float* __restrict__ W1,
                                const float* __restrict__ W2, const float* __restrict__ W3,
                                const float* __restrict__ W4, const float* __restrict__ W5,
                                ushort* __restrict__ out, int* __restrict__ cnt) {
    if (blockIdx.y == 0) {
        int z = blockIdx.x * 256 + threadIdx.x;
        if (z < NTOT_DST) cnt[z] = 0;
    }
    const float* W; int Ndim; ushort* o;
    switch (blockIdx.y) {
        case 0: W = W0; Ndim = 256; o = out; break;
        case 1: W = W1; Ndim = 256; o = out + 65536; break;
        case 2: W = W2; Ndim = 256; o = out + 131072; break;
        case 3: W = W3; Ndim = 256; o = out + 196608; break;
        case 4: W = W4; Ndim = 64;  o = out + 262144; break;
        default: W = W5; Ndim = 64; o = out + 278528; break;
    }
    int id = blockIdx.x * 256 + threadIdx.x;  // id = n*256 + k
    int n = id >> 8;
    int k = id & 255;
    if (n >= Ndim) return;
    o[id] = f2bf(W[k * Ndim + n]);
}

// ---------------------------------------------------------------------------
// Batched CSR build over all 3 layers (cnt/cursor concatenated; eidx global)
// ---------------------------------------------------------------------------
__global__ void hist3_kernel(const int* __restrict__ d0, int E0,
                             const int* __restrict__ d1, int E1,
                             const int* __restrict__ d2, int E2,
                             int* __restrict__ cnt) {
    int layer = blockIdx.y;
    const int* dst; int E; int base;
    if (layer == 0)      { dst = d0; E = E0; base = 0; }
    else if (layer == 1) { dst = d1; E = E1; base = N1_DST; }
    else                 { dst = d2; E = E2; base = N1_DST + N2_DST; }
    int e = blockIdx.x * 256 + threadIdx.x;
    if (e < E) atomicAdd(&cnt[base + dst[e]], 1);
}

__global__ void fill3_kernel(const int* __restrict__ s0, const int* __restrict__ d0, int E0,
                             const int* __restrict__ s1, const int* __restrict__ d1, int E1,
                             const int* __restrict__ s2, const int* __restrict__ d2, int E2,
                             int* __restrict__ cursor, int* __restrict__ eidx) {
    int layer = blockIdx.y;
    const int* src; const int* dst; int E; int base;
    if (layer == 0)      { src = s0; dst = d0; E = E0; base = 0; }
    else if (layer == 1) { src = s1; dst = d1; E = E1; base = N1_DST; }
    else                 { src = s2; dst = d2; E = E2; base = N1_DST + N2_DST; }
    int e = blockIdx.x * 256 + threadIdx.x;
    if (e < E) {
        int p = atomicAdd(&cursor[base + dst[e]], 1);
        eidx[p] = src[e];
    }
}

// ---------------------------------------------------------------------------
// 3-phase coalesced exclusive scan (n multiple of 4; n <= 64*1024)
// ---------------------------------------------------------------------------
__global__ void scan_phase_a(const int* __restrict__ cnt, int* __restrict__ partial, int n) {
    __shared__ int red[4];
    int t = threadIdx.x;
    int i = blockIdx.x * 1024 + t * 4;
    int s = 0;
    if (i + 3 < n) {
        int4 v = *(const int4*)(cnt + i);
        s = v.x + v.y + v.z + v.w;
    }
#pragma unroll
    for (int d = 32; d; d >>= 1) s += __shfl_down(s, d, 64);
    if ((t & 63) == 0) red[t >> 6] = s;
    __syncthreads();
    if (t == 0) partial[blockIdx.x] = red[0] + red[1] + red[2] + red[3];
}

__global__ void scan_phase_b(int* __restrict__ partial, int nb) {
    int t = threadIdx.x;  // 64 threads
    int own = (t < nb) ? partial[t] : 0;
    int v = own;
#pragma unroll
    for (int d = 1; d < 64; d <<= 1) {
        int u = __shfl_up(v, d, 64);
        if (t >= d) v += u;
    }
    if (t < nb) partial[t] = v - own;  // exclusive
}

__global__ void scan_phase_c(const int* __restrict__ cnt, const int* __restrict__ partial,
                             int* __restrict__ off, int* __restrict__ cursor, int n) {
    __shared__ int tsum[256];
    int t = threadIdx.x;
    int i = blockIdx.x * 1024 + t * 4;
    int4 c = make_int4(0, 0, 0, 0);
    if (i + 3 < n) c = *(const int4*)(cnt + i);
    int s = c.x + c.y + c.z + c.w;
    tsum[t] = s;
    __syncthreads();
#pragma unroll
    for (int d = 1; d < 256; d <<= 1) {
        int u = (t >= d) ? tsum[t - d] : 0;
        __syncthreads();
        tsum[t] += u;
        __syncthreads();
    }
    int base = partial[blockIdx.x] + tsum[t] - s;
    if (i + 3 < n) {
        int4 ov;
        ov.x = base;
        ov.y = ov.x + c.x;
        ov.z = ov.y + c.y;
        ov.w = ov.z + c.z;
        *(int4*)(off + i) = ov;
        *(int4*)(cursor + i) = ov;
        if (i + 4 == n) off[n] = ov.w + c.w;
    }
}

// ---------------------------------------------------------------------------
// Gather-mean, bf16 in -> bf16 out. One wave per dst; lane owns 4 feats.
// Branch-free masked 4-wide batches: the tail is one predicated batch instead
// of up to 3 serial dependent loads (each ~600-900 cy).
// ---------------------------------------------------------------------------
__global__ void gather_mean_bf16_kernel(const ushort* __restrict__ h,
                                        const int* __restrict__ off,
                                        const int* __restrict__ eidx,
                                        ushort* __restrict__ hn,
                                        int num_dst) {
    int w = blockIdx.x * 4 + (threadIdx.x >> 6);
    int lane = threadIdx.x & 63;
    if (w >= num_dst) return;
    int beg = off[w];
    int end = off[w + 1];
    float a0 = 0.f, a1 = 0.f, a2 = 0.f, a3 = 0.f;
    for (int i = beg; i < end; i += 4) {
        int rem = end - i;  // >= 1
        int j1 = i + (rem > 1 ? 1 : 0);
        int j2 = i + (rem > 2 ? 2 : 0);
        int j3 = i + (rem > 3 ? 3 : 0);
        float m1 = rem > 1 ? 1.f : 0.f;
        float m2 = rem > 2 ? 1.f : 0.f;
        float m3 = rem > 3 ? 1.f : 0.f;
        int s0 = eidx[i], s1 = eidx[j1], s2 = eidx[j2], s3 = eidx[j3];
        ushort4 v0 = ((const ushort4*)(h + (size_t)s0 * DH))[lane];
        ushort4 v1 = ((const ushort4*)(h + (size_t)s1 * DH))[lane];
        ushort4 v2 = ((const ushort4*)(h + (size_t)s2 * DH))[lane];
        ushort4 v3 = ((const ushort4*)(h + (size_t)s3 * DH))[lane];
        a0 += bf2f(v0.x) + m1 * bf2f(v1.x) + m2 * bf2f(v2.x) + m3 * bf2f(v3.x);
        a1 += bf2f(v0.y) + m1 * bf2f(v1.y) + m2 * bf2f(v2.y) + m3 * bf2f(v3.y);
        a2 += bf2f(v0.z) + m1 * bf2f(v1.z) + m2 * bf2f(v2.z) + m3 * bf2f(v3.z);
        a3 += bf2f(v0.w) + m1 * bf2f(v1.w) + m2 * bf2f(v2.w) + m3 * bf2f(v3.w);
    }
    float inv = 1.0f / fmaxf((float)(end - beg), 1.0f);
    ushort4 o;
    o.x = f2bf(a0 * inv); o.y = f2bf(a1 * inv);
    o.z = f2bf(a2 * inv); o.w = f2bf(a3 * inv);
    *(ushort4*)(hn + (size_t)w * DH + lane * 4) = o;
}

// ---------------------------------------------------------------------------
// Merged-dual MFMA GEMM: C[M,N] = Ad@Ws + An@Wn + bias (K=256), both passes
// in ONE k-loop (32 MFMA per barrier pair). Staging via global_load_lds
// width-16 into LINEAR LDS tiles [rows][32] (LDK=32 shorts, 64B rows).
// Since gload_lds forbids padding, ds_read bank conflicts are handled by the
// both-sides XOR swizzle (rule 21): 16B segment s ^= ((row>>1)&3) applied to
// the per-lane GLOBAL source address at stage time and to the ds_read addr.
// Unswizzled would be 8-way (2.94x, m136); swizzled is 2-way (free).
// BM = MT*64 (4 waves x MT*16 rows), BN = NT*16. M-tail: staged row clamped
// to M-1 (MFMA output rows are independent; clamped rows never written).
// ---------------------------------------------------------------------------
template <int MT, int NT, bool RELU, bool OUT_BF16>
__global__ __launch_bounds__(256) void gemm_dual(const ushort* __restrict__ Ad,
                                                 const ushort* __restrict__ An,
                                                 const ushort* __restrict__ Wst,
                                                 const ushort* __restrict__ Wnt,
                                                 const float* __restrict__ bias,
                                                 void* __restrict__ Cv,
                                                 int M, int N) {
    const int K = 256;
    const int BM = MT * 64;
    const int BN = NT * 16;
    __shared__ __align__(16) ushort lds[(2 * BM + 2 * BN) * 32];
    ushort* Asd = lds;
    ushort* Asn = lds + BM * 32;
    ushort* Bss = lds + 2 * BM * 32;
    ushort* Bsn = lds + 2 * BM * 32 + BN * 32;

    int tid  = threadIdx.x;
    int lane = tid & 63;
    int wid  = tid >> 6;
    int q    = lane >> 4;
    int mr   = lane & 15;
    int row0 = blockIdx.y * BM;
    int col0 = blockIdx.x * BN;

    f32x4 acc[MT][NT];
#pragma unroll
    for (int i = 0; i < MT; ++i)
#pragma unroll
        for (int j = 0; j < NT; ++j) acc[i][j] = (f32x4){0.f, 0.f, 0.f, 0.f};

    for (int k0 = 0; k0 < K; k0 += 32) {
        // Stage A tiles (BM x 32, clamped rows), both matrices.
#pragma unroll
        for (int c = 0; c < MT; ++c) {
            int chunk = c * 256 + tid;          // 16B chunk index in tile
            int r   = chunk >> 2;               // tile row
            int sg  = (chunk & 3) ^ ((r >> 1) & 3);  // swizzled global segment
            int row = row0 + r;
            if (row > M - 1) row = M - 1;
            const ushort* gd = Ad + (size_t)row * K + k0 + sg * 8;
            const ushort* gn = An + (size_t)row * K + k0 + sg * 8;
            int cb = (c * 256 + (tid & ~63)) * 8;  // wave-uniform LDS base (ushorts)
            gload16(gd, Asd + cb);
            gload16(gn, Asn + cb);
        }
        // Stage B tiles (BN x 32), both weight matrices. Rows always valid.
#pragma unroll
        for (int c = 0; c < NT / 4; ++c) {
            int chunk = c * 256 + tid;
            int r  = chunk >> 2;
            int sg = (chunk & 3) ^ ((r >> 1) & 3);
            const ushort* gs = Wst + (size_t)(col0 + r) * K + k0 + sg * 8;
            const ushort* gw = Wnt + (size_t)(col0 + r) * K + k0 + sg * 8;
            int cb = (c * 256 + (tid & ~63)) * 8;
            gload16(gs, Bss + cb);
            gload16(gw, Bsn + cb);
        }
        __syncthreads();  // compiler drains vmcnt(0) before s_barrier

        short8 ad[MT], an[MT];
#pragma unroll
        for (int mt = 0; mt < MT; ++mt) {
            int rho = wid * (MT * 16) + mt * 16 + mr;
            int o   = rho * 32 + ((q ^ ((rho >> 1) & 3)) * 8);
            ad[mt] = *(const short8*)(Asd + o);
            an[mt] = *(const short8*)(Asn + o);
        }
#pragma unroll
        for (int nt = 0; nt < NT; ++nt) {
            int rho = nt * 16 + mr;
            int o   = rho * 32 + ((q ^ ((rho >> 1) & 3)) * 8);
            short8 bs = *(const short8*)(Bss + o);
            short8 bn = *(const short8*)(Bsn + o);
#pragma unroll
            for (int mt = 0; mt < MT; ++mt) {
                acc[mt][nt] = __builtin_amdgcn_mfma_f32_16x16x32_bf16(
                    ad[mt], bs, acc[mt][nt], 0, 0, 0);
                acc[mt][nt] = __builtin_amdgcn_mfma_f32_16x16x32_bf16(
                    an[mt], bn, acc[mt][nt], 0, 0, 0);
            }
        }
        __syncthreads();
    }

    // Epilogue: C/D layout col = lane&15, row = quad*4 + reg
#pragma unroll
    for (int mt = 0; mt < MT; ++mt) {
#pragma unroll
        for (int i = 0; i < 4; ++i) {
            int row = row0 + wid * (MT * 16) + mt * 16 + q * 4 + i;
            if (row >= M) continue;
#pragma unroll
            for (int nt = 0; nt < NT; ++nt) {
                int col = col0 + nt * 16 + mr;
                float v = acc[mt][nt][i] + bias[col];
                if (RELU) v = fmaxf(v, 0.0f);
                if (OUT_BF16) ((ushort*)Cv)[(size_t)row * N + col] = f2bf(v);
                else          ((float*)Cv)[(size_t)row * N + col] = v;
            }
        }
    }
}

extern "C" void kernel_launch(void* const* d_in, const int* in_sizes, int n_in,
                              void* d_out, int out_size, void* d_ws, size_t ws_size,
                              hipStream_t stream) {
    const float* x    = (const float*)d_in[0];
    const int* src0   = (const int*)d_in[1];
    const int* dst0   = (const int*)d_in[2];
    const int* src1   = (const int*)d_in[3];
    const int* dst1   = (const int*)d_in[4];
    const int* src2   = (const int*)d_in[5];
    const int* dst2   = (const int*)d_in[6];
    const float* Ws0  = (const float*)d_in[10];
    const float* Wn0  = (const float*)d_in[11];
    const float* b0   = (const float*)d_in[12];
    const float* Ws1  = (const float*)d_in[13];
    const float* Wn1  = (const float*)d_in[14];
    const float* b1   = (const float*)d_in[15];
    const float* Ws2  = (const float*)d_in[16];
    const float* Wn2  = (const float*)d_in[17];
    const float* b2   = (const float*)d_in[18];
    float* out = (float*)d_out;

    int E0 = in_sizes[1];
    int E1 = in_sizes[3];
    int E2 = in_sizes[5];

    // Workspace layout (shorts first, then ints; all 16B aligned)
    ushort* wsu  = (ushort*)d_ws;
    ushort* xb   = wsu;                               // N0*256 (all of x, bf16)
    ushort* hn0b = xb   + (size_t)N0_SRC * DH;        // N1*256
    ushort* h1b  = hn0b + (size_t)N1_DST * DH;        // N1*256
    ushort* hn1b = h1b  + (size_t)N1_DST * DH;        // N2*256
    ushort* h2b  = hn1b + (size_t)N2_DST * DH;        // N2*256
    ushort* hn2b = h2b  + (size_t)N2_DST * DH;        // N3*256
    ushort* Wt   = hn2b + (size_t)N3_DST * DH;        // 294912 shorts (6 weights)
    ushort* Ws0t = Wt;
    ushort* Wn0t = Wt + 65536;
    ushort* Ws1t = Wt + 131072;
    ushort* Wn1t = Wt + 196608;
    ushort* Ws2t = Wt + 262144;
    ushort* Wn2t = Wt + 278528;
    int* cnt     = (int*)(Wt + 294912);               // NTOT_DST
    int* off     = cnt + NTOT_DST;                    // NTOT_DST+1 (+pad)
    int* cursor  = off + NTOT_DST + 4;                // NTOT_DST
    int* eidx    = cursor + NTOT_DST;                 // EMAX_TOT
    int* partial = eidx + EMAX_TOT;                   // 64 block partials

    // --- One-time per call: convert ALL of x and all weights to bf16.
    //     transpose_w_all also zeroes cnt (replaces hipMemsetAsync). ---
    long nxb = (long)N0_SRC * DH;
    f32_to_bf16_kernel<<<(int)((nxb / 4 + 255) / 256), 256, 0, stream>>>(x, xb, nxb);
    transpose_w_all<<<dim3(256, 6), 256, 0, stream>>>(Ws0, Wn0, Ws1, Wn1, Ws2, Wn2, Wt, cnt);

    // --- Batched CSR build for all 3 layers ---
    int Emax = max(max(E0, E1), E2);
    int nb = (NTOT_DST + 1023) / 1024;  // = 64
    hist3_kernel<<<dim3((Emax + 255) / 256, 3), 256, 0, stream>>>(dst0, E0, dst1, E1, dst2, E2, cnt);
    scan_phase_a<<<nb, 256, 0, stream>>>(cnt, partial, NTOT_DST);
    scan_phase_b<<<1, 64, 0, stream>>>(partial, nb);
    scan_phase_c<<<nb, 256, 0, stream>>>(cnt, partial, off, cursor, NTOT_DST);
    fill3_kernel<<<dim3((Emax + 255) / 256, 3), 256, 0, stream>>>(
        src0, dst0, E0, src1, dst1, E1, src2, dst2, E2, cursor, eidx);

    const int* off0 = off;
    const int* off1 = off + N1_DST;
    const int* off2 = off + N1_DST + N2_DST;

    // ---- Layer 0: x -> h1 ----
    gather_mean_bf16_kernel<<<(N1_DST + 3) / 4, 256, 0, stream>>>(xb, off0, eidx, hn0b, N1_DST);
    gemm_dual<2, 8, false, true><<<dim3(DH / 128, (N1_DST + 127) / 128), 256, 0, stream>>>(
        xb, hn0b, Ws0t, Wn0t, b0, h1b, N1_DST, DH);

    // ---- Layer 1: h1 -> h2 (ReLU on output) ----
    gather_mean_bf16_kernel<<<(N2_DST + 3) / 4, 256, 0, stream>>>(h1b, off1, eidx, hn1b, N2_DST);
    gemm_dual<2, 8, true, true><<<dim3(DH / 128, (N2_DST + 127) / 128), 256, 0, stream>>>(
        h1b, hn1b, Ws1t, Wn1t, b1, h2b, N2_DST, DH);

    // ---- Layer 2: h2 -> out (fp32 output, BM=64 for 2x parallelism) ----
    gather_mean_bf16_kernel<<<(N3_DST + 3) / 4, 256, 0, stream>>>(h2b, off2, eidx, hn2b, N3_DST);
    gemm_dual<1, 4, false, false><<<dim3(DOUT / 64, (N3_DST + 63) / 64), 256, 0, stream>>>(
        h2b, hn2b, Ws2t, Wn2t, b2, out, N3_DST, DOUT);
}